// Round 1
// baseline (245.072 us; speedup 1.0000x reference)
//
#include <hip/hip_runtime.h>
#include <hip/hip_bf16.h>

typedef __attribute__((ext_vector_type(8))) short bf16x8;
typedef __attribute__((ext_vector_type(4))) float f32x4;
typedef unsigned short u16;
typedef unsigned int u32;

#define B_ 2
#define S_ 2048
#define D_ 1024
#define H_ 16
#define HD_ 64

__device__ __forceinline__ u16 f2bf(float f) {
    u32 u = __float_as_uint(f);
    u += 0x7FFF + ((u >> 16) & 1);   // RNE
    return (u16)(u >> 16);
}

// ---------------- fp32 -> bf16 elementwise ----------------
__global__ __launch_bounds__(256) void cvt_bf16(const float* __restrict__ in,
                                                u16* __restrict__ out) {
    int i = blockIdx.x * 256 + threadIdx.x;
    float4 v = ((const float4*)in)[i];
    ushort4 o;
    o.x = f2bf(v.x); o.y = f2bf(v.y); o.z = f2bf(v.z); o.w = f2bf(v.w);
    ((ushort4*)out)[i] = o;
}

// ---------------- fp32 [R][C] -> bf16 [C][R] transpose ----------------
__global__ __launch_bounds__(256) void tconv(const float* __restrict__ in,
                                             u16* __restrict__ out, int R, int C) {
    __shared__ float t[32][33];
    int c0 = blockIdx.x * 32, r0 = blockIdx.y * 32;
    int lx = threadIdx.x & 31, ly = threadIdx.x >> 5;
#pragma unroll
    for (int i = 0; i < 4; ++i)
        t[ly + i * 8][lx] = in[(size_t)(r0 + ly + i * 8) * C + c0 + lx];
    __syncthreads();
#pragma unroll
    for (int i = 0; i < 4; ++i)
        out[(size_t)(c0 + ly + i * 8) * R + r0 + lx] = f2bf(t[lx][ly + i * 8]);
}

// ---------------- bf16 GEMM, B transposed ([N][K]) ----------------
// MODE 0: epilogue scatters into Q(x0.125)/K/V [B][H][S][HD] bf16 (N=3072)
// MODE 1: epilogue writes fp32 out [M][N] + bias (N=1024)
template <int MODE>
__global__ __launch_bounds__(256) void gemm_bt(
    const u16* __restrict__ A, const u16* __restrict__ Bt,
    const float* __restrict__ bias, int K, int N,
    u16* __restrict__ oQ, u16* __restrict__ oK, u16* __restrict__ oV,
    float* __restrict__ oF) {
    __shared__ u16 Al[128][72];
    __shared__ u16 Bl[128][72];
    const int tid = threadIdx.x;
    const int lane = tid & 63, w = tid >> 6;
    const int wm = w >> 1, wn = w & 1;
    const int l15 = lane & 15, lg = lane >> 4;
    const int m0 = blockIdx.y * 128, n0 = blockIdx.x * 128;
    f32x4 acc[4][4] = {};
    const int srow = tid >> 3, sc8 = (tid & 7) * 8;

    for (int k0 = 0; k0 < K; k0 += 64) {
        __syncthreads();
#pragma unroll
        for (int it = 0; it < 4; ++it) {
            int r = srow + it * 32;
            *(uint4*)&Al[r][sc8] = *(const uint4*)&A[(size_t)(m0 + r) * K + k0 + sc8];
            *(uint4*)&Bl[r][sc8] = *(const uint4*)&Bt[(size_t)(n0 + r) * K + k0 + sc8];
        }
        __syncthreads();
#pragma unroll
        for (int g = 0; g < 2; ++g) {
            bf16x8 af[4], bfr[4];
#pragma unroll
            for (int t = 0; t < 4; ++t) {
                af[t]  = *(const bf16x8*)&Al[wm * 64 + t * 16 + l15][g * 32 + lg * 8];
                bfr[t] = *(const bf16x8*)&Bl[wn * 64 + t * 16 + l15][g * 32 + lg * 8];
            }
#pragma unroll
            for (int mt = 0; mt < 4; ++mt)
#pragma unroll
                for (int nt = 0; nt < 4; ++nt)
                    acc[mt][nt] = __builtin_amdgcn_mfma_f32_16x16x32_bf16(
                        af[mt], bfr[nt], acc[mt][nt], 0, 0, 0);
        }
    }

#pragma unroll
    for (int mt = 0; mt < 4; ++mt) {
#pragma unroll
        for (int nt = 0; nt < 4; ++nt) {
            const int n_g = n0 + wn * 64 + nt * 16 + l15;
            const int m_b = m0 + wm * 64 + mt * 16 + lg * 4;
            const float bs = bias[n_g];
            if (MODE == 0) {
                const int which = n_g >> 10;          // 0=q 1=k 2=v
                const int nn = n_g & 1023;
                const int h = nn >> 6, hd = nn & 63;
                u16* dst = which == 0 ? oQ : (which == 1 ? oK : oV);
                const float scale = which == 0 ? 0.125f : 1.0f;
#pragma unroll
                for (int r = 0; r < 4; ++r) {
                    const int m_g = m_b + r;
                    const int bb = m_g >> 11, s = m_g & 2047;
                    dst[((size_t)(bb * H_ + h) * S_ + s) * HD_ + hd] =
                        f2bf((acc[mt][nt][r] + bs) * scale);
                }
            } else {
#pragma unroll
                for (int r = 0; r < 4; ++r)
                    oF[(size_t)(m_b + r) * N + n_g] = acc[mt][nt][r] + bs;
            }
        }
    }
}

// ---------------- flash attention, causal ----------------
// grid = B*H * (S/64); 4 waves, wave w owns q rows q0+w*16 .. +15
__global__ __launch_bounds__(256) void attn_kern(
    const u16* __restrict__ Q, const u16* __restrict__ Kp,
    const u16* __restrict__ Vp, u16* __restrict__ Om) {
    __shared__ u16 Kl[64][72];
    __shared__ u16 Vt[64][72];   // transposed: [hd][key]
    __shared__ u16 Pl[64][72];   // per-wave 16-row slices
    const int tid = threadIdx.x;
    const int lane = tid & 63, w = tid >> 6;
    const int l15 = lane & 15, lg = lane >> 4;
    const int bh = blockIdx.x >> 5, qb = blockIdx.x & 31;
    const int b = bh >> 4, h = bh & 15;
    const int q0 = qb * 64;
    const size_t base = (size_t)bh * (S_ * HD_);

    bf16x8 qf[2];
    {
        const int qrow = q0 + w * 16 + l15;
#pragma unroll
        for (int g = 0; g < 2; ++g)
            qf[g] = *(const bf16x8*)&Q[base + (size_t)qrow * HD_ + g * 32 + lg * 8];
    }
    f32x4 acc_o[4] = {};
    float m_run[4], l_run[4];
#pragma unroll
    for (int r = 0; r < 4; ++r) { m_run[r] = -1e30f; l_run[r] = 0.0f; }

    const int srow = tid >> 3, sc8 = (tid & 7) * 8;

    for (int kt = 0; kt <= q0; kt += 64) {
        __syncthreads();
#pragma unroll
        for (int it = 0; it < 2; ++it) {
            int r = srow + it * 32;
            *(uint4*)&Kl[r][sc8] = *(const uint4*)&Kp[base + (size_t)(kt + r) * HD_ + sc8];
            bf16x8 vv = *(const bf16x8*)&Vp[base + (size_t)(kt + r) * HD_ + sc8];
#pragma unroll
            for (int e = 0; e < 8; ++e) Vt[sc8 + e][r] = (u16)vv[e];
        }
        __syncthreads();

        f32x4 sc[4] = {};
#pragma unroll
        for (int g = 0; g < 2; ++g) {
#pragma unroll
            for (int nt = 0; nt < 4; ++nt) {
                bf16x8 kb = *(const bf16x8*)&Kl[nt * 16 + l15][g * 32 + lg * 8];
                sc[nt] = __builtin_amdgcn_mfma_f32_16x16x32_bf16(qf[g], kb, sc[nt], 0, 0, 0);
            }
        }
        if (kt == q0) {
#pragma unroll
            for (int nt = 0; nt < 4; ++nt) {
                int col = kt + nt * 16 + l15;
#pragma unroll
                for (int r = 0; r < 4; ++r) {
                    int row = q0 + w * 16 + lg * 4 + r;
                    if (col > row) sc[nt][r] = -1e30f;
                }
            }
        }
#pragma unroll
        for (int r = 0; r < 4; ++r) {
            float mx = fmaxf(fmaxf(sc[0][r], sc[1][r]), fmaxf(sc[2][r], sc[3][r]));
#pragma unroll
            for (int msk = 1; msk < 16; msk <<= 1) mx = fmaxf(mx, __shfl_xor(mx, msk, 64));
            float m_new = fmaxf(m_run[r], mx);
            float alpha = __expf(m_run[r] - m_new);
            float ssum = 0.f;
#pragma unroll
            for (int nt = 0; nt < 4; ++nt) {
                float p = __expf(sc[nt][r] - m_new);
                sc[nt][r] = p;
                ssum += p;
            }
#pragma unroll
            for (int msk = 1; msk < 16; msk <<= 1) ssum += __shfl_xor(ssum, msk, 64);
            l_run[r] = l_run[r] * alpha + ssum;
            m_run[r] = m_new;
#pragma unroll
            for (int d = 0; d < 4; ++d) acc_o[d][r] *= alpha;
        }
        // P (D-layout) -> LDS -> A-layout
#pragma unroll
        for (int nt = 0; nt < 4; ++nt)
#pragma unroll
            for (int r = 0; r < 4; ++r)
                Pl[w * 16 + lg * 4 + r][nt * 16 + l15] = f2bf(sc[nt][r]);
        __syncthreads();
#pragma unroll
        for (int g = 0; g < 2; ++g) {
            bf16x8 pa = *(const bf16x8*)&Pl[w * 16 + l15][g * 32 + lg * 8];
#pragma unroll
            for (int d = 0; d < 4; ++d) {
                bf16x8 vb = *(const bf16x8*)&Vt[d * 16 + l15][g * 32 + lg * 8];
                acc_o[d] = __builtin_amdgcn_mfma_f32_16x16x32_bf16(pa, vb, acc_o[d], 0, 0, 0);
            }
        }
    }
#pragma unroll
    for (int d = 0; d < 4; ++d)
#pragma unroll
        for (int r = 0; r < 4; ++r) {
            int row = q0 + w * 16 + lg * 4 + r;
            float v = acc_o[d][r] / l_run[r];
            Om[((size_t)b * S_ + row) * D_ + h * HD_ + d * 16 + l15] = f2bf(v);
        }
}

extern "C" void kernel_launch(void* const* d_in, const int* in_sizes, int n_in,
                              void* d_out, int out_size, void* d_ws, size_t ws_size,
                              hipStream_t stream) {
    const float* x      = (const float*)d_in[0];
    const float* w_attn = (const float*)d_in[1];
    const float* b_attn = (const float*)d_in[2];
    const float* w_proj = (const float*)d_in[3];
    const float* b_proj = (const float*)d_in[4];
    float* out = (float*)d_out;

    char* ws = (char*)d_ws;
    const size_t XE = (size_t)B_ * S_ * D_;          // 4194304
    u16* x_bf = (u16*)ws;            ws += XE * 2;   // also reused as merged
    u16* waT  = (u16*)ws;            ws += (size_t)3 * D_ * D_ * 2;
    u16* wpT  = (u16*)ws;            ws += (size_t)D_ * D_ * 2;
    u16* Qb   = (u16*)ws;            ws += XE * 2;
    u16* Kb   = (u16*)ws;            ws += XE * 2;
    u16* Vb   = (u16*)ws;            ws += XE * 2;
    u16* Mg   = x_bf;                // alias: x_bf dead after GEMM1

    cvt_bf16<<<(int)(XE / 4 / 256), 256, 0, stream>>>(x, x_bf);
    tconv<<<dim3(3 * D_ / 32, D_ / 32), 256, 0, stream>>>(w_attn, waT, D_, 3 * D_);
    tconv<<<dim3(D_ / 32, D_ / 32), 256, 0, stream>>>(w_proj, wpT, D_, D_);

    gemm_bt<0><<<dim3(3 * D_ / 128, B_ * S_ / 128), 256, 0, stream>>>(
        x_bf, waT, b_attn, D_, 3 * D_, Qb, Kb, Vb, nullptr);

    attn_kern<<<B_ * H_ * (S_ / 64), 256, 0, stream>>>(Qb, Kb, Vb, Mg);

    gemm_bt<1><<<dim3(D_ / 128, B_ * S_ / 128), 256, 0, stream>>>(
        Mg, wpT, b_proj, D_, D_, nullptr, nullptr, nullptr, out);
}